// Round 3
// baseline (818.300 us; speedup 1.0000x reference)
//
#include <hip/hip_runtime.h>
#include <hip/hip_bf16.h>
#include <cstdint>
#include <cstddef>

// Problem constants
#define SEQLEN   2048
#define HIDDEN   2048
#define INTER    4096
#define NHEADS   64
#define NSTATE   64
#define CONVD    4224          // INTER + 2*64
#define LDPROJ   8448          // PROJ (8384) padded to 128-multiple
#define NCHUNK   32
#define CHUNK    64

typedef __attribute__((ext_vector_type(8))) short bf16x8_t;
typedef __attribute__((ext_vector_type(4))) float f32x4_t;

__device__ __forceinline__ void cp16(void* lds, const void* g) {
    __builtin_amdgcn_global_load_lds(
        (const __attribute__((address_space(1))) unsigned int*)g,
        (__attribute__((address_space(3))) unsigned int*)lds, 16, 0, 0);
}

// ---------------- split fp32 -> bf16 (hi, lo) ----------------
__global__ void k_split(const float* __restrict__ in, unsigned short* __restrict__ hi,
                        unsigned short* __restrict__ lo, long nvalid, long ntotal) {
    long i = (long)blockIdx.x * 256 + threadIdx.x;
    if (i >= ntotal) return;
    float x = (i < nvalid) ? in[i] : 0.0f;
    __hip_bfloat16 h = __float2bfloat16(x);
    float hf = __bfloat162float(h);
    __hip_bfloat16 l = __float2bfloat16(x - hf);
    hi[i] = *reinterpret_cast<unsigned short*>(&h);
    lo[i] = *reinterpret_cast<unsigned short*>(&l);
}

__global__ void k_split_hi(const float* __restrict__ in, unsigned short* __restrict__ hi,
                           long nvalid, long ntotal) {
    long i = (long)blockIdx.x * 256 + threadIdx.x;
    if (i >= ntotal) return;
    float x = (i < nvalid) ? in[i] : 0.0f;
    __hip_bfloat16 h = __float2bfloat16(x);
    hi[i] = *reinterpret_cast<unsigned short*>(&h);
}

__global__ void k_split_lo(const float* __restrict__ in, unsigned short* __restrict__ lo,
                           long nvalid, long ntotal) {
    long i = (long)blockIdx.x * 256 + threadIdx.x;
    if (i >= ntotal) return;
    float x = (i < nvalid) ? in[i] : 0.0f;
    __hip_bfloat16 h = __float2bfloat16(x);
    float hf = __bfloat162float(h);
    __hip_bfloat16 l = __float2bfloat16(x - hf);
    lo[i] = *reinterpret_cast<unsigned short*>(&l);
}

// ---------------- split-bf16 GEMM: C[M,N] = A[M,K] * B[N,K]^T ----------------
// 128x128 tile per block, flat grid with M-major strip swizzle (strip_w N-blocks).
// Blocks with bn >= split_col do 3-term Ootomo split (ah*bh+ah*bl+al*bh);
// blocks below do plain bf16-hi (1 MFMA).
// LDS layout: chunk c (16 rows x 32 k) at [c*512 elems]; within chunk element
// (row,k8) at (k8*16 + (row&15))*8 — staged so fragment ds_read_b128 address is
// exactly chunk*1024B + lane*16B (bank-conflict-free).
__global__ __launch_bounds__(256, 2)
void k_gemm_split(const unsigned short* __restrict__ Ah, const unsigned short* __restrict__ Al,
                  const unsigned short* __restrict__ Bh, const unsigned short* __restrict__ Bl,
                  float* __restrict__ C, int K, int ldc,
                  int mb_count, int strip_w, int split_col) {
    __shared__ unsigned short sA[2][128 * 32];
    __shared__ unsigned short sB[2][128 * 32];

    const int tid  = threadIdx.x;
    const int lane = tid & 63;
    const int w    = tid >> 6;
    const int wm   = w >> 1, wn = w & 1;

    // strip swizzle: M-major within strips of strip_w N-blocks
    const int span  = mb_count * strip_w;
    const int strip = blockIdx.x / span;
    const int within = blockIdx.x % span;
    const int mblk = within % mb_count;
    const int nblk = strip * strip_w + within / mb_count;
    const long bm  = (long)mblk * 128;
    const long bn  = (long)nblk * 128;
    const bool do_lo = (bn >= (long)split_col);

    f32x4_t acc[4][4];
#pragma unroll
    for (int i = 0; i < 4; ++i)
#pragma unroll
        for (int j = 0; j < 4; ++j) acc[i][j] = (f32x4_t){0.f, 0.f, 0.f, 0.f};

    const int srow = lane & 15;          // staging row-in-chunk
    const int c8   = (lane >> 4) << 3;   // staging k element offset 0/8/16/24

    for (int k0 = 0; k0 < K; k0 += 32) {
#pragma unroll
        for (int j = 0; j < 2; ++j) {
            const int chunk = j * 4 + w;          // 0..7, wave-uniform
            const int r     = chunk * 16 + srow;  // tile row
            const long gA   = (bm + r) * (long)K + k0 + c8;
            const long gB   = (bn + r) * (long)K + k0 + c8;
            const int lbase = chunk * 512;        // elements
            cp16(&sA[0][lbase], Ah + gA);
            cp16(&sB[0][lbase], Bh + gB);
            if (do_lo) {
                cp16(&sA[1][lbase], Al + gA);
                cp16(&sB[1][lbase], Bl + gB);
            }
        }
        __syncthreads();

        bf16x8_t fah[4], fbh[4];
#pragma unroll
        for (int mi = 0; mi < 4; ++mi)
            fah[mi] = *(const bf16x8_t*)&sA[0][(wm * 4 + mi) * 512 + lane * 8];
#pragma unroll
        for (int ni = 0; ni < 4; ++ni)
            fbh[ni] = *(const bf16x8_t*)&sB[0][(wn * 4 + ni) * 512 + lane * 8];

        if (do_lo) {
            bf16x8_t fal[4], fbl[4];
#pragma unroll
            for (int mi = 0; mi < 4; ++mi)
                fal[mi] = *(const bf16x8_t*)&sA[1][(wm * 4 + mi) * 512 + lane * 8];
#pragma unroll
            for (int ni = 0; ni < 4; ++ni)
                fbl[ni] = *(const bf16x8_t*)&sB[1][(wn * 4 + ni) * 512 + lane * 8];
#pragma unroll
            for (int mi = 0; mi < 4; ++mi)
#pragma unroll
                for (int ni = 0; ni < 4; ++ni) {
                    acc[mi][ni] = __builtin_amdgcn_mfma_f32_16x16x32_bf16(fah[mi], fbh[ni], acc[mi][ni], 0, 0, 0);
                    acc[mi][ni] = __builtin_amdgcn_mfma_f32_16x16x32_bf16(fah[mi], fbl[ni], acc[mi][ni], 0, 0, 0);
                    acc[mi][ni] = __builtin_amdgcn_mfma_f32_16x16x32_bf16(fal[mi], fbh[ni], acc[mi][ni], 0, 0, 0);
                }
        } else {
#pragma unroll
            for (int mi = 0; mi < 4; ++mi)
#pragma unroll
                for (int ni = 0; ni < 4; ++ni)
                    acc[mi][ni] = __builtin_amdgcn_mfma_f32_16x16x32_bf16(fah[mi], fbh[ni], acc[mi][ni], 0, 0, 0);
        }
        __syncthreads();
    }

    // epilogue: D mapping col = lane&15, row = (lane>>4)*4 + reg  [m89-verified]
    const int col = lane & 15;
    const int rq  = (lane >> 4) << 2;
#pragma unroll
    for (int mi = 0; mi < 4; ++mi)
#pragma unroll
        for (int ni = 0; ni < 4; ++ni) {
            long mb_ = bm + wm * 64 + mi * 16 + rq;
            long nb_ = bn + wn * 64 + ni * 16 + col;
#pragma unroll
            for (int r = 0; r < 4; ++r) C[(mb_ + r) * (long)ldc + nb_] = acc[mi][ni][r];
        }
}

// ---------------- causal depthwise conv (K=4) + SiLU ----------------
__global__ void k_conv(const float* __restrict__ proj, const float* __restrict__ cw,
                       const float* __restrict__ cb, float* __restrict__ xbc) {
    int c = blockIdx.x * 256 + threadIdx.x;
    int t = blockIdx.y;
    if (c >= CONVD) return;
    float acc = cb[c];
#pragma unroll
    for (int k = 0; k < 4; ++k) {
        int tt = t - 3 + k;
        if (tt >= 0) acc += proj[(size_t)tt * LDPROJ + INTER + c] * cw[c * 4 + k];
    }
    float s = acc / (1.f + expf(-acc));
    xbc[(size_t)t * CONVD + c] = s;
}

// ---------------- dt = softplus(raw + bias); cd = within-chunk inclusive cumsum ----
__global__ __launch_bounds__(256)
void k_cum(const float* __restrict__ proj, const float* __restrict__ dtb,
           float* __restrict__ dt, float* __restrict__ cd) {
    const int tid  = threadIdx.x;
    const int lane = tid & 63;
    const int wid  = blockIdx.x * 4 + (tid >> 6);   // 0..2047
    const int c    = wid >> 6;                       // chunk
    const int h    = wid & 63;                       // head
    const int t    = c * CHUNK + lane;
    float raw = proj[(size_t)t * LDPROJ + 8320 + h] + dtb[h];
    float sp  = (raw > 20.f) ? raw : log1pf(expf(raw));
    float x = sp;
#pragma unroll
    for (int off = 1; off < 64; off <<= 1) {
        float v = __shfl_up(x, off, 64);
        if (lane >= off) x += v;
    }
    dt[t * 64 + h] = sp;
    cd[t * 64 + h] = x;
}

// ---------------- SSD intra-chunk: G = tril(CB^T ∘ decay), Y=G@X, M=(wB)^T@X ------
__global__ __launch_bounds__(256, 2)
void k_ssdA(const float* __restrict__ xbc, const float* __restrict__ dt,
            const float* __restrict__ cd, const float* __restrict__ alog,
            const float* __restrict__ Dp, float* __restrict__ y,
            float* __restrict__ M) {
    __shared__ float Xs[64][68];
    __shared__ float Bs[64][68];
    __shared__ float Cs[64][68];   // reused as Gs after G computed
    __shared__ float dts[64], cds[64], wts[64];
    float (*Gs)[68] = Cs;

    const int c = blockIdx.x, h = blockIdx.y;
    const int tid = threadIdx.x;
    const int tr = tid >> 4, tc = tid & 15;
    const int t0 = c * CHUNK;
    const float A = -__expf(alog[h]);

    for (int i = tid; i < 4096; i += 256) {
        int t = i >> 6, j = i & 63;
        size_t base = (size_t)(t0 + t) * CONVD;
        Xs[t][j] = xbc[base + h * 64 + j];
        Bs[t][j] = xbc[base + INTER + j];
        Cs[t][j] = xbc[base + INTER + 64 + j];
    }
    if (tid < 64) {
        dts[tid] = dt[(t0 + tid) * 64 + h];
        cds[tid] = cd[(t0 + tid) * 64 + h];
    }
    __syncthreads();
    if (tid < 64) wts[tid] = __expf(A * (cds[63] - cds[tid])) * dts[tid];

    float g[4][4];
#pragma unroll
    for (int i = 0; i < 4; ++i)
#pragma unroll
        for (int j = 0; j < 4; ++j) g[i][j] = 0.f;
    for (int n = 0; n < 64; n += 4) {
        float4 cv[4], bv[4];
#pragma unroll
        for (int i = 0; i < 4; ++i) cv[i] = *(const float4*)&Cs[tr * 4 + i][n];
#pragma unroll
        for (int j = 0; j < 4; ++j) bv[j] = *(const float4*)&Bs[tc * 4 + j][n];
#pragma unroll
        for (int i = 0; i < 4; ++i)
#pragma unroll
            for (int j = 0; j < 4; ++j)
                g[i][j] += cv[i].x * bv[j].x + cv[i].y * bv[j].y +
                           cv[i].z * bv[j].z + cv[i].w * bv[j].w;
    }
    __syncthreads();
#pragma unroll
    for (int i = 0; i < 4; ++i) {
        int t = tr * 4 + i;
#pragma unroll
        for (int j = 0; j < 4; ++j) {
            int tau = tc * 4 + j;
            float v = (tau <= t) ? g[i][j] * __expf(A * (cds[t] - cds[tau])) * dts[tau] : 0.f;
            Gs[t][tau] = v;
        }
    }
    __syncthreads();

    float accY[4][4], accM[4][4];
#pragma unroll
    for (int i = 0; i < 4; ++i)
#pragma unroll
        for (int j = 0; j < 4; ++j) { accY[i][j] = 0.f; accM[i][j] = 0.f; }

    for (int tau = 0; tau < 64; tau += 4) {
        float4 gv[4], xv[4];
#pragma unroll
        for (int i = 0; i < 4; ++i) gv[i] = *(const float4*)&Gs[tr * 4 + i][tau];
#pragma unroll
        for (int k = 0; k < 4; ++k) xv[k] = *(const float4*)&Xs[tau + k][tc * 4];
#pragma unroll
        for (int i = 0; i < 4; ++i) {
            accY[i][0] += gv[i].x * xv[0].x + gv[i].y * xv[1].x + gv[i].z * xv[2].x + gv[i].w * xv[3].x;
            accY[i][1] += gv[i].x * xv[0].y + gv[i].y * xv[1].y + gv[i].z * xv[2].y + gv[i].w * xv[3].y;
            accY[i][2] += gv[i].x * xv[0].z + gv[i].y * xv[1].z + gv[i].z * xv[2].z + gv[i].w * xv[3].z;
            accY[i][3] += gv[i].x * xv[0].w + gv[i].y * xv[1].w + gv[i].z * xv[2].w + gv[i].w * xv[3].w;
        }
#pragma unroll
        for (int k = 0; k < 4; ++k) {
            float wv = wts[tau + k];
            float4 bv = *(const float4*)&Bs[tau + k][tr * 4];
            float4 xk = xv[k];
            float wb0 = wv * bv.x, wb1 = wv * bv.y, wb2 = wv * bv.z, wb3 = wv * bv.w;
            accM[0][0] += wb0 * xk.x; accM[0][1] += wb0 * xk.y; accM[0][2] += wb0 * xk.z; accM[0][3] += wb0 * xk.w;
            accM[1][0] += wb1 * xk.x; accM[1][1] += wb1 * xk.y; accM[1][2] += wb1 * xk.z; accM[1][3] += wb1 * xk.w;
            accM[2][0] += wb2 * xk.x; accM[2][1] += wb2 * xk.y; accM[2][2] += wb2 * xk.z; accM[2][3] += wb2 * xk.w;
            accM[3][0] += wb3 * xk.x; accM[3][1] += wb3 * xk.y; accM[3][2] += wb3 * xk.z; accM[3][3] += wb3 * xk.w;
        }
    }

    const float Dv = Dp[h];
#pragma unroll
    for (int i = 0; i < 4; ++i) {
        int t = tr * 4 + i;
        float4 o;
        o.x = accY[i][0] + Dv * Xs[t][tc * 4 + 0];
        o.y = accY[i][1] + Dv * Xs[t][tc * 4 + 1];
        o.z = accY[i][2] + Dv * Xs[t][tc * 4 + 2];
        o.w = accY[i][3] + Dv * Xs[t][tc * 4 + 3];
        *(float4*)&y[(size_t)(t0 + t) * INTER + h * 64 + tc * 4] = o;
    }
    size_t mbase = ((size_t)(c * 64 + h)) << 12;
#pragma unroll
    for (int i = 0; i < 4; ++i) {
        float4 o = { accM[i][0], accM[i][1], accM[i][2], accM[i][3] };
        *(float4*)&M[mbase + (size_t)(tr * 4 + i) * 64 + tc * 4] = o;
    }
}

// ---------------- sequential chunk-state propagation ----------------
__global__ __launch_bounds__(256)
void k_state(const float* __restrict__ M, const float* __restrict__ cd,
             const float* __restrict__ alog, float* __restrict__ Sprev) {
    const int g  = blockIdx.x * 256 + threadIdx.x;
    const int h  = g >> 12;
    const int np = g & 4095;
    const float A = -__expf(alog[h]);
    float s = 0.f;
#pragma unroll 1
    for (int c = 0; c < NCHUNK; ++c) {
        size_t idx = (((size_t)(c * 64 + h)) << 12) + np;
        Sprev[idx] = s;
        float decay = __expf(A * cd[((c * CHUNK + 63) * 64) + h]);
        s = decay * s + M[idx];
    }
}

// ---------------- SSD inter-chunk: y += exp(A*cd_t) * C_t . S_prev ----------------
__global__ __launch_bounds__(256, 2)
void k_ssdC(const float* __restrict__ xbc, const float* __restrict__ cd,
            const float* __restrict__ alog, const float* __restrict__ Sprev,
            float* __restrict__ y) {
    __shared__ float Ss[64][68];
    __shared__ float Cs[64][68];
    __shared__ float cds[64];
    const int c = blockIdx.x, h = blockIdx.y;
    const int tid = threadIdx.x;
    const int tr = tid >> 4, tc = tid & 15;
    const int t0 = c * CHUNK;
    const float A = -__expf(alog[h]);

    size_t sbase = ((size_t)(c * 64 + h)) << 12;
    for (int i = tid; i < 4096; i += 256) {
        int n = i >> 6, p = i & 63;
        Ss[n][p] = Sprev[sbase + i];
        Cs[n][p] = xbc[(size_t)(t0 + n) * CONVD + INTER + 64 + p];
    }
    if (tid < 64) cds[tid] = cd[(t0 + tid) * 64 + h];
    __syncthreads();

    float acc[4][4];
#pragma unroll
    for (int i = 0; i < 4; ++i)
#pragma unroll
        for (int j = 0; j < 4; ++j) acc[i][j] = 0.f;

    for (int n = 0; n < 64; n += 4) {
        float4 cv[4], sv[4];
#pragma unroll
        for (int i = 0; i < 4; ++i) cv[i] = *(const float4*)&Cs[tr * 4 + i][n];
#pragma unroll
        for (int k = 0; k < 4; ++k) sv[k] = *(const float4*)&Ss[n + k][tc * 4];
#pragma unroll
        for (int i = 0; i < 4; ++i) {
            acc[i][0] += cv[i].x * sv[0].x + cv[i].y * sv[1].x + cv[i].z * sv[2].x + cv[i].w * sv[3].x;
            acc[i][1] += cv[i].x * sv[0].y + cv[i].y * sv[1].y + cv[i].z * sv[2].y + cv[i].w * sv[3].y;
            acc[i][2] += cv[i].x * sv[0].z + cv[i].y * sv[1].z + cv[i].z * sv[2].z + cv[i].w * sv[3].z;
            acc[i][3] += cv[i].x * sv[0].w + cv[i].y * sv[1].w + cv[i].z * sv[2].w + cv[i].w * sv[3].w;
        }
    }

#pragma unroll
    for (int i = 0; i < 4; ++i) {
        int t = tr * 4 + i;
        float sc = __expf(A * cds[t]);
        size_t yi = (size_t)(t0 + t) * INTER + h * 64 + tc * 4;
        float4 cur = *(const float4*)&y[yi];
        cur.x += sc * acc[i][0];
        cur.y += sc * acc[i][1];
        cur.z += sc * acc[i][2];
        cur.w += sc * acc[i][3];
        *(float4*)&y[yi] = cur;
    }
}

// ---------------- RMSNorm * silu(gate), then split to bf16 hi/lo ----------------
__global__ __launch_bounds__(256)
void k_norm(const float* __restrict__ y, const float* __restrict__ proj,
            const float* __restrict__ nw, unsigned short* __restrict__ ygh,
            unsigned short* __restrict__ ygl) {
    __shared__ float red[4];
    const int t = blockIdx.x, tid = threadIdx.x;
    float sum = 0.f;
    for (int i = tid; i < INTER; i += 256) {
        float v = y[(size_t)t * INTER + i];
        sum += v * v;
    }
#pragma unroll
    for (int off = 32; off >= 1; off >>= 1) sum += __shfl_xor(sum, off, 64);
    if ((tid & 63) == 0) red[tid >> 6] = sum;
    __syncthreads();
    float var = (red[0] + red[1] + red[2] + red[3]) * (1.f / INTER);
    float rs  = rsqrtf(var + 1e-6f);
    for (int i = tid; i < INTER; i += 256) {
        float v = y[(size_t)t * INTER + i] * rs * nw[i];
        float g = proj[(size_t)t * LDPROJ + i];
        float o = v * (g / (1.f + expf(-g)));
        __hip_bfloat16 hh = __float2bfloat16(o);
        float hf = __bfloat162float(hh);
        __hip_bfloat16 ll = __float2bfloat16(o - hf);
        ygh[(size_t)t * INTER + i] = *reinterpret_cast<unsigned short*>(&hh);
        ygl[(size_t)t * INTER + i] = *reinterpret_cast<unsigned short*>(&ll);
    }
}

// ---------------- workspace layout (bytes) ----------------
#define OFF_HSHI  ((size_t)0)
#define OFF_HSLO  ((size_t)8388608)
#define OFF_YGH   ((size_t)0)
#define OFF_W1HI  ((size_t)16777216)
#define OFF_W1LO  ((size_t)(16777216 + 34603008))    // now only 1 MB used (rows 8192..8447)
#define OFF_M     ((size_t)16777216)                  // NOTE: M overlaps W1HI? -- no: see below
#define OFF_SPREV ((size_t)50331648)
#define OFF_W2HI  ((size_t)16777216)
#define OFF_W2LO  ((size_t)33554432)
#define OFF_PROJ  ((size_t)85983232)
#define OFF_XBC   ((size_t)155189248)
#define OFF_DT    ((size_t)189792256)
#define OFF_CD    ((size_t)190316544)
#define OFF_Y     ((size_t)190840832)
#define OFF_YGL   ((size_t)224395264)
// M region [16MB,50MB) overlaps w1_hi [16MB,51.4MB): w1_hi is dead once gemm1
// completes; k_ssdA (writer of M) runs strictly after gemm1. w1_lo lives at
// 51.4MB (1MB used) and is also dead by then. Total footprint ~230 MB.

extern "C" void kernel_launch(void* const* d_in, const int* in_sizes, int n_in,
                              void* d_out, int out_size, void* d_ws, size_t ws_size,
                              hipStream_t stream) {
    (void)in_sizes; (void)n_in; (void)out_size; (void)ws_size;
    const float* hs   = (const float*)d_in[0];
    const float* w1   = (const float*)d_in[1];
    const float* cw   = (const float*)d_in[2];
    const float* cb   = (const float*)d_in[3];
    const float* dtb  = (const float*)d_in[4];
    const float* alog = (const float*)d_in[5];
    const float* Dp   = (const float*)d_in[6];
    const float* nw   = (const float*)d_in[7];
    const float* w2   = (const float*)d_in[8];
    float* out = (float*)d_out;
    char* ws = (char*)d_ws;

    unsigned short* hs_hi = (unsigned short*)(ws + OFF_HSHI);
    unsigned short* hs_lo = (unsigned short*)(ws + OFF_HSLO);
    unsigned short* w1_hi = (unsigned short*)(ws + OFF_W1HI);
    unsigned short* w1_lo = (unsigned short*)(ws + OFF_W1LO);
    unsigned short* w2_hi = (unsigned short*)(ws + OFF_W2HI);
    unsigned short* w2_lo = (unsigned short*)(ws + OFF_W2LO);
    unsigned short* ygh   = (unsigned short*)(ws + OFF_YGH);
    unsigned short* ygl   = (unsigned short*)(ws + OFF_YGL);
    float* proj  = (float*)(ws + OFF_PROJ);
    float* xbc   = (float*)(ws + OFF_XBC);
    float* dtv   = (float*)(ws + OFF_DT);
    float* cdv   = (float*)(ws + OFF_CD);
    float* y     = (float*)(ws + OFF_Y);
    float* M     = (float*)(ws + OFF_M);
    float* Sprev = (float*)(ws + OFF_SPREV);

    // 1) splits: hs hi+lo; w1 hi (full, zero-padded); w1 lo only rows [8192,8448)
    k_split<<<16384, 256, 0, stream>>>(hs, hs_hi, hs_lo, 4194304L, 4194304L);
    k_split_hi<<<67584, 256, 0, stream>>>(w1, w1_hi, 17170432L, 17301504L);
    k_split_lo<<<2048, 256, 0, stream>>>(w1 + (size_t)8192 * 2048, w1_lo, 393216L, 524288L);

    // 2) in_proj: cols [0,8192) bf16-hi only; cols [8192,8448) 3-term split
    //    Bl indexed from row 8192 -> shift base pointer
    const unsigned short* w1_lo_base = w1_lo - (size_t)8192 * 2048;
    k_gemm_split<<<1056, 256, 0, stream>>>(hs_hi, hs_lo, w1_hi, w1_lo_base, proj,
                                           HIDDEN, LDPROJ, 16, 6, 8192);

    // 3) conv + silu; dt softplus + within-chunk cumsum
    k_conv<<<dim3(17, SEQLEN), 256, 0, stream>>>(proj, cw, cb, xbc);
    k_cum<<<512, 256, 0, stream>>>(proj, dtb, dtv, cdv);

    // 4) chunked SSD
    k_ssdA<<<dim3(NCHUNK, NHEADS), 256, 0, stream>>>(xbc, dtv, cdv, alog, Dp, y, M);
    k_state<<<1024, 256, 0, stream>>>(M, cdv, alog, Sprev);
    k_ssdC<<<dim3(NCHUNK, NHEADS), 256, 0, stream>>>(xbc, cdv, alog, Sprev, y);

    // 5) RMSNorm * silu(gate) + split to bf16
    k_norm<<<SEQLEN, 256, 0, stream>>>(y, proj, nw, ygh, ygl);

    // 6) split out_proj weights (w1/M regions dead by now)
    k_split<<<32768, 256, 0, stream>>>(w2, w2_hi, w2_lo, 8388608L, 8388608L);

    // 7) out = yg @ w2^T, full 3-term
    k_gemm_split<<<256, 256, 0, stream>>>(ygh, ygl, w2_hi, w2_lo, out,
                                          INTER, HIDDEN, 16, 4, 0);
}

// Round 4
// 685.622 us; speedup vs baseline: 1.1935x; 1.1935x over previous
//
#include <hip/hip_runtime.h>
#include <hip/hip_bf16.h>
#include <cstdint>
#include <cstddef>

// Problem constants
#define SEQLEN   2048
#define HIDDEN   2048
#define INTER    4096
#define NHEADS   64
#define NSTATE   64
#define CONVD    4224          // INTER + 2*64
#define LDPROJ   8448          // PROJ (8384) padded to 128-multiple
#define NCHUNK   32
#define CHUNK    64

typedef __attribute__((ext_vector_type(8))) short bf16x8_t;
typedef __attribute__((ext_vector_type(4))) float f32x4_t;

__device__ __forceinline__ void cp16(void* lds, const void* g) {
    __builtin_amdgcn_global_load_lds(
        (const __attribute__((address_space(1))) unsigned int*)g,
        (__attribute__((address_space(3))) unsigned int*)lds, 16, 0, 0);
}

// ---------------- split fp32 -> bf16 (hi, lo) ----------------
__global__ void k_split(const float* __restrict__ in, unsigned short* __restrict__ hi,
                        unsigned short* __restrict__ lo, long nvalid, long ntotal) {
    long i = (long)blockIdx.x * 256 + threadIdx.x;
    if (i >= ntotal) return;
    float x = (i < nvalid) ? in[i] : 0.0f;
    __hip_bfloat16 h = __float2bfloat16(x);
    float hf = __bfloat162float(h);
    __hip_bfloat16 l = __float2bfloat16(x - hf);
    hi[i] = *reinterpret_cast<unsigned short*>(&h);
    lo[i] = *reinterpret_cast<unsigned short*>(&l);
}

__global__ void k_split_hi(const float* __restrict__ in, unsigned short* __restrict__ hi,
                           long nvalid, long ntotal) {
    long i = (long)blockIdx.x * 256 + threadIdx.x;
    if (i >= ntotal) return;
    float x = (i < nvalid) ? in[i] : 0.0f;
    __hip_bfloat16 h = __float2bfloat16(x);
    hi[i] = *reinterpret_cast<unsigned short*>(&h);
}

__global__ void k_split_lo(const float* __restrict__ in, unsigned short* __restrict__ lo,
                           long nvalid, long ntotal) {
    long i = (long)blockIdx.x * 256 + threadIdx.x;
    if (i >= ntotal) return;
    float x = (i < nvalid) ? in[i] : 0.0f;
    __hip_bfloat16 h = __float2bfloat16(x);
    float hf = __bfloat162float(h);
    __hip_bfloat16 l = __float2bfloat16(x - hf);
    lo[i] = *reinterpret_cast<unsigned short*>(&l);
}

// ---------------- split-bf16 GEMM: C[M,N] = A[M,K] * B[N,K]^T ----------------
// 128x128 tile, 1-barrier software-pipelined K-loop with double-buffered
// global_load_lds prefetch. Blocks with bn >= split_col do 3-term Ootomo
// split; others plain bf16-hi. LDS staged so fragment ds_read_b128 is
// chunk*1024B + lane*16B (conflict-free, verified R3: SQ_LDS_BANK_CONFLICT=0).
__global__ __launch_bounds__(256, 2)
void k_gemm_split(const unsigned short* __restrict__ Ah, const unsigned short* __restrict__ Al,
                  const unsigned short* __restrict__ Bh, const unsigned short* __restrict__ Bl,
                  float* __restrict__ C, int K, int ldc,
                  int mb_count, int strip_w, int split_col) {
    __shared__ unsigned short sA[2][2][4096];   // [buf][hi/lo][128x32]
    __shared__ unsigned short sB[2][2][4096];

    const int tid  = threadIdx.x;
    const int lane = tid & 63;
    const int w    = tid >> 6;
    const int wm   = w >> 1, wn = w & 1;

    const int span   = mb_count * strip_w;
    const int strip  = blockIdx.x / span;
    const int within = blockIdx.x % span;
    const int mblk = within % mb_count;
    const int nblk = strip * strip_w + within / mb_count;
    const long bm  = (long)mblk * 128;
    const long bn  = (long)nblk * 128;
    const bool do_lo = (bn >= (long)split_col);

    f32x4_t acc[4][4];
#pragma unroll
    for (int i = 0; i < 4; ++i)
#pragma unroll
        for (int j = 0; j < 4; ++j) acc[i][j] = (f32x4_t){0.f, 0.f, 0.f, 0.f};

    const int srow = lane & 15;          // staging row-in-chunk
    const int c8   = (lane >> 4) << 3;   // staging k element offset

    auto stage = [&](int k0, int buf) {
#pragma unroll
        for (int j = 0; j < 2; ++j) {
            const int chunk = j * 4 + w;          // wave-uniform
            const int r     = chunk * 16 + srow;
            const long gA   = (bm + r) * (long)K + k0 + c8;
            const long gB   = (bn + r) * (long)K + k0 + c8;
            const int lbase = chunk * 512;
            cp16(&sA[buf][0][lbase], Ah + gA);
            cp16(&sB[buf][0][lbase], Bh + gB);
            if (do_lo) {
                cp16(&sA[buf][1][lbase], Al + gA);
                cp16(&sB[buf][1][lbase], Bl + gB);
            }
        }
    };

    const int NK = K >> 5;
    stage(0, 0);   // prologue

    for (int it = 0; it < NK; ++it) {
        const int cur = it & 1;
        __syncthreads();   // drains own vmcnt -> buf[cur] ready (all waves); lgkm -> buf[cur^1] reads done

        bf16x8_t fah[4], fbh[4], fal[4], fbl[4];
#pragma unroll
        for (int mi = 0; mi < 4; ++mi)
            fah[mi] = *(const bf16x8_t*)&sA[cur][0][(wm * 4 + mi) * 512 + lane * 8];
#pragma unroll
        for (int ni = 0; ni < 4; ++ni)
            fbh[ni] = *(const bf16x8_t*)&sB[cur][0][(wn * 4 + ni) * 512 + lane * 8];
        if (do_lo) {
#pragma unroll
            for (int mi = 0; mi < 4; ++mi)
                fal[mi] = *(const bf16x8_t*)&sA[cur][1][(wm * 4 + mi) * 512 + lane * 8];
#pragma unroll
            for (int ni = 0; ni < 4; ++ni)
                fbl[ni] = *(const bf16x8_t*)&sB[cur][1][(wn * 4 + ni) * 512 + lane * 8];
        }

        if (it + 1 < NK) stage((it + 1) << 5, cur ^ 1);   // async prefetch into other buffer

        if (do_lo) {
#pragma unroll
            for (int mi = 0; mi < 4; ++mi)
#pragma unroll
                for (int ni = 0; ni < 4; ++ni) {
                    acc[mi][ni] = __builtin_amdgcn_mfma_f32_16x16x32_bf16(fah[mi], fbh[ni], acc[mi][ni], 0, 0, 0);
                    acc[mi][ni] = __builtin_amdgcn_mfma_f32_16x16x32_bf16(fah[mi], fbl[ni], acc[mi][ni], 0, 0, 0);
                    acc[mi][ni] = __builtin_amdgcn_mfma_f32_16x16x32_bf16(fal[mi], fbh[ni], acc[mi][ni], 0, 0, 0);
                }
        } else {
#pragma unroll
            for (int mi = 0; mi < 4; ++mi)
#pragma unroll
                for (int ni = 0; ni < 4; ++ni)
                    acc[mi][ni] = __builtin_amdgcn_mfma_f32_16x16x32_bf16(fah[mi], fbh[ni], acc[mi][ni], 0, 0, 0);
        }
    }

    // epilogue: D mapping col = lane&15, row = (lane>>4)*4 + reg  [m89-verified]
    const int col = lane & 15;
    const int rq  = (lane >> 4) << 2;
#pragma unroll
    for (int mi = 0; mi < 4; ++mi)
#pragma unroll
        for (int ni = 0; ni < 4; ++ni) {
            long mb_ = bm + wm * 64 + mi * 16 + rq;
            long nb_ = bn + wn * 64 + ni * 16 + col;
#pragma unroll
            for (int r = 0; r < 4; ++r) C[(mb_ + r) * (long)ldc + nb_] = acc[mi][ni][r];
        }
}

// ---------------- causal depthwise conv (K=4) + SiLU: 8 timesteps/thread ----------
__global__ __launch_bounds__(256)
void k_conv(const float* __restrict__ proj, const float* __restrict__ cw,
            const float* __restrict__ cb, float* __restrict__ xbc) {
    int c  = blockIdx.x * 256 + threadIdx.x;
    int t0 = blockIdx.y * 8;
    if (c >= CONVD) return;
    const float cw0 = cw[c * 4], cw1 = cw[c * 4 + 1], cw2 = cw[c * 4 + 2], cw3 = cw[c * 4 + 3];
    const float b = cb[c];
    float h[11];
#pragma unroll
    for (int i = 0; i < 11; ++i) {
        int tt = t0 - 3 + i;
        h[i] = (tt >= 0) ? proj[(size_t)tt * LDPROJ + INTER + c] : 0.f;
    }
#pragma unroll
    for (int k = 0; k < 8; ++k) {
        float acc = b + h[k] * cw0 + h[k + 1] * cw1 + h[k + 2] * cw2 + h[k + 3] * cw3;
        float s = acc / (1.f + expf(-acc));
        xbc[(size_t)(t0 + k) * CONVD + c] = s;
    }
}

// ---------------- dt = softplus(raw + bias); cd = within-chunk inclusive cumsum ----
__global__ __launch_bounds__(256)
void k_cum(const float* __restrict__ proj, const float* __restrict__ dtb,
           float* __restrict__ dt, float* __restrict__ cd) {
    const int tid  = threadIdx.x;
    const int lane = tid & 63;
    const int wid  = blockIdx.x * 4 + (tid >> 6);
    const int c    = wid >> 6;
    const int h    = wid & 63;
    const int t    = c * CHUNK + lane;
    float raw = proj[(size_t)t * LDPROJ + 8320 + h] + dtb[h];
    float sp  = (raw > 20.f) ? raw : log1pf(expf(raw));
    float x = sp;
#pragma unroll
    for (int off = 1; off < 64; off <<= 1) {
        float v = __shfl_up(x, off, 64);
        if (lane >= off) x += v;
    }
    dt[t * 64 + h] = sp;
    cd[t * 64 + h] = x;
}

// ---------------- SSD intra-chunk: G = tril(CB^T ∘ decay), Y=G@X, M=(wB)^T@X ------
__global__ __launch_bounds__(256, 2)
void k_ssdA(const float* __restrict__ xbc, const float* __restrict__ dt,
            const float* __restrict__ cd, const float* __restrict__ alog,
            const float* __restrict__ Dp, float* __restrict__ y,
            float* __restrict__ M) {
    __shared__ float Xs[64][68];
    __shared__ float Bs[64][68];
    __shared__ float Cs[64][68];
    __shared__ float dts[64], cds[64], wts[64];
    float (*Gs)[68] = Cs;

    const int c = blockIdx.x, h = blockIdx.y;
    const int tid = threadIdx.x;
    const int tr = tid >> 4, tc = tid & 15;
    const int t0 = c * CHUNK;
    const float A = -__expf(alog[h]);

    for (int i = tid; i < 4096; i += 256) {
        int t = i >> 6, j = i & 63;
        size_t base = (size_t)(t0 + t) * CONVD;
        Xs[t][j] = xbc[base + h * 64 + j];
        Bs[t][j] = xbc[base + INTER + j];
        Cs[t][j] = xbc[base + INTER + 64 + j];
    }
    if (tid < 64) {
        dts[tid] = dt[(t0 + tid) * 64 + h];
        cds[tid] = cd[(t0 + tid) * 64 + h];
    }
    __syncthreads();
    if (tid < 64) wts[tid] = __expf(A * (cds[63] - cds[tid])) * dts[tid];

    float g[4][4];
#pragma unroll
    for (int i = 0; i < 4; ++i)
#pragma unroll
        for (int j = 0; j < 4; ++j) g[i][j] = 0.f;
    for (int n = 0; n < 64; n += 4) {
        float4 cv[4], bv[4];
#pragma unroll
        for (int i = 0; i < 4; ++i) cv[i] = *(const float4*)&Cs[tr * 4 + i][n];
#pragma unroll
        for (int j = 0; j < 4; ++j) bv[j] = *(const float4*)&Bs[tc * 4 + j][n];
#pragma unroll
        for (int i = 0; i < 4; ++i)
#pragma unroll
            for (int j = 0; j < 4; ++j)
                g[i][j] += cv[i].x * bv[j].x + cv[i].y * bv[j].y +
                           cv[i].z * bv[j].z + cv[i].w * bv[j].w;
    }
    __syncthreads();
#pragma unroll
    for (int i = 0; i < 4; ++i) {
        int t = tr * 4 + i;
#pragma unroll
        for (int j = 0; j < 4; ++j) {
            int tau = tc * 4 + j;
            float v = (tau <= t) ? g[i][j] * __expf(A * (cds[t] - cds[tau])) * dts[tau] : 0.f;
            Gs[t][tau] = v;
        }
    }
    __syncthreads();

    float accY[4][4], accM[4][4];
#pragma unroll
    for (int i = 0; i < 4; ++i)
#pragma unroll
        for (int j = 0; j < 4; ++j) { accY[i][j] = 0.f; accM[i][j] = 0.f; }

    for (int tau = 0; tau < 64; tau += 4) {
        float4 gv[4], xv[4];
#pragma unroll
        for (int i = 0; i < 4; ++i) gv[i] = *(const float4*)&Gs[tr * 4 + i][tau];
#pragma unroll
        for (int k = 0; k < 4; ++k) xv[k] = *(const float4*)&Xs[tau + k][tc * 4];
#pragma unroll
        for (int i = 0; i < 4; ++i) {
            accY[i][0] += gv[i].x * xv[0].x + gv[i].y * xv[1].x + gv[i].z * xv[2].x + gv[i].w * xv[3].x;
            accY[i][1] += gv[i].x * xv[0].y + gv[i].y * xv[1].y + gv[i].z * xv[2].y + gv[i].w * xv[3].y;
            accY[i][2] += gv[i].x * xv[0].z + gv[i].y * xv[1].z + gv[i].z * xv[2].z + gv[i].w * xv[3].z;
            accY[i][3] += gv[i].x * xv[0].w + gv[i].y * xv[1].w + gv[i].z * xv[2].w + gv[i].w * xv[3].w;
        }
#pragma unroll
        for (int k = 0; k < 4; ++k) {
            float wv = wts[tau + k];
            float4 bv = *(const float4*)&Bs[tau + k][tr * 4];
            float4 xk = xv[k];
            float wb0 = wv * bv.x, wb1 = wv * bv.y, wb2 = wv * bv.z, wb3 = wv * bv.w;
            accM[0][0] += wb0 * xk.x; accM[0][1] += wb0 * xk.y; accM[0][2] += wb0 * xk.z; accM[0][3] += wb0 * xk.w;
            accM[1][0] += wb1 * xk.x; accM[1][1] += wb1 * xk.y; accM[1][2] += wb1 * xk.z; accM[1][3] += wb1 * xk.w;
            accM[2][0] += wb2 * xk.x; accM[2][1] += wb2 * xk.y; accM[2][2] += wb2 * xk.z; accM[2][3] += wb2 * xk.w;
            accM[3][0] += wb3 * xk.x; accM[3][1] += wb3 * xk.y; accM[3][2] += wb3 * xk.z; accM[3][3] += wb3 * xk.w;
        }
    }

    const float Dv = Dp[h];
#pragma unroll
    for (int i = 0; i < 4; ++i) {
        int t = tr * 4 + i;
        float4 o;
        o.x = accY[i][0] + Dv * Xs[t][tc * 4 + 0];
        o.y = accY[i][1] + Dv * Xs[t][tc * 4 + 1];
        o.z = accY[i][2] + Dv * Xs[t][tc * 4 + 2];
        o.w = accY[i][3] + Dv * Xs[t][tc * 4 + 3];
        *(float4*)&y[(size_t)(t0 + t) * INTER + h * 64 + tc * 4] = o;
    }
    size_t mbase = ((size_t)(c * 64 + h)) << 12;
#pragma unroll
    for (int i = 0; i < 4; ++i) {
        float4 o = { accM[i][0], accM[i][1], accM[i][2], accM[i][3] };
        *(float4*)&M[mbase + (size_t)(tr * 4 + i) * 64 + tc * 4] = o;
    }
}

// ---------------- sequential chunk-state propagation ----------------
__global__ __launch_bounds__(256)
void k_state(const float* __restrict__ M, const float* __restrict__ cd,
             const float* __restrict__ alog, float* __restrict__ Sprev) {
    const int g  = blockIdx.x * 256 + threadIdx.x;
    const int h  = g >> 12;
    const int np = g & 4095;
    const float A = -__expf(alog[h]);
    float s = 0.f;
#pragma unroll 1
    for (int c = 0; c < NCHUNK; ++c) {
        size_t idx = (((size_t)(c * 64 + h)) << 12) + np;
        Sprev[idx] = s;
        float decay = __expf(A * cd[((c * CHUNK + 63) * 64) + h]);
        s = decay * s + M[idx];
    }
}

// ---------------- SSD inter-chunk: y += exp(A*cd_t) * C_t . S_prev ----------------
__global__ __launch_bounds__(256, 2)
void k_ssdC(const float* __restrict__ xbc, const float* __restrict__ cd,
            const float* __restrict__ alog, const float* __restrict__ Sprev,
            float* __restrict__ y) {
    __shared__ float Ss[64][68];
    __shared__ float Cs[64][68];
    __shared__ float cds[64];
    const int c = blockIdx.x, h = blockIdx.y;
    const int tid = threadIdx.x;
    const int tr = tid >> 4, tc = tid & 15;
    const int t0 = c * CHUNK;
    const float A = -__expf(alog[h]);

    size_t sbase = ((size_t)(c * 64 + h)) << 12;
    for (int i = tid; i < 4096; i += 256) {
        int n = i >> 6, p = i & 63;
        Ss[n][p] = Sprev[sbase + i];
        Cs[n][p] = xbc[(size_t)(t0 + n) * CONVD + INTER + 64 + p];
    }
    if (tid < 64) cds[tid] = cd[(t0 + tid) * 64 + h];
    __syncthreads();

    float acc[4][4];
#pragma unroll
    for (int i = 0; i < 4; ++i)
#pragma unroll
        for (int j = 0; j < 4; ++j) acc[i][j] = 0.f;

    for (int n = 0; n < 64; n += 4) {
        float4 cv[4], sv[4];
#pragma unroll
        for (int i = 0; i < 4; ++i) cv[i] = *(const float4*)&Cs[tr * 4 + i][n];
#pragma unroll
        for (int k = 0; k < 4; ++k) sv[k] = *(const float4*)&Ss[n + k][tc * 4];
#pragma unroll
        for (int i = 0; i < 4; ++i) {
            acc[i][0] += cv[i].x * sv[0].x + cv[i].y * sv[1].x + cv[i].z * sv[2].x + cv[i].w * sv[3].x;
            acc[i][1] += cv[i].x * sv[0].y + cv[i].y * sv[1].y + cv[i].z * sv[2].y + cv[i].w * sv[3].y;
            acc[i][2] += cv[i].x * sv[0].z + cv[i].y * sv[1].z + cv[i].z * sv[2].z + cv[i].w * sv[3].z;
            acc[i][3] += cv[i].x * sv[0].w + cv[i].y * sv[1].w + cv[i].z * sv[2].w + cv[i].w * sv[3].w;
        }
    }

#pragma unroll
    for (int i = 0; i < 4; ++i) {
        int t = tr * 4 + i;
        float sc = __expf(A * cds[t]);
        size_t yi = (size_t)(t0 + t) * INTER + h * 64 + tc * 4;
        float4 cur = *(const float4*)&y[yi];
        cur.x += sc * acc[i][0];
        cur.y += sc * acc[i][1];
        cur.z += sc * acc[i][2];
        cur.w += sc * acc[i][3];
        *(float4*)&y[yi] = cur;
    }
}

// ---------------- RMSNorm * silu(gate), then split to bf16 hi/lo ----------------
__global__ __launch_bounds__(256)
void k_norm(const float* __restrict__ y, const float* __restrict__ proj,
            const float* __restrict__ nw, unsigned short* __restrict__ ygh,
            unsigned short* __restrict__ ygl) {
    __shared__ float red[4];
    const int t = blockIdx.x, tid = threadIdx.x;
    float sum = 0.f;
    for (int i = tid; i < INTER; i += 256) {
        float v = y[(size_t)t * INTER + i];
        sum += v * v;
    }
#pragma unroll
    for (int off = 32; off >= 1; off >>= 1) sum += __shfl_xor(sum, off, 64);
    if ((tid & 63) == 0) red[tid >> 6] = sum;
    __syncthreads();
    float var = (red[0] + red[1] + red[2] + red[3]) * (1.f / INTER);
    float rs  = rsqrtf(var + 1e-6f);
    for (int i = tid; i < INTER; i += 256) {
        float v = y[(size_t)t * INTER + i] * rs * nw[i];
        float g = proj[(size_t)t * LDPROJ + i];
        float o = v * (g / (1.f + expf(-g)));
        __hip_bfloat16 hh = __float2bfloat16(o);
        float hf = __bfloat162float(hh);
        __hip_bfloat16 ll = __float2bfloat16(o - hf);
        ygh[(size_t)t * INTER + i] = *reinterpret_cast<unsigned short*>(&hh);
        ygl[(size_t)t * INTER + i] = *reinterpret_cast<unsigned short*>(&ll);
    }
}

// ---------------- workspace layout (bytes) ----------------
#define OFF_HSHI  ((size_t)0)
#define OFF_HSLO  ((size_t)8388608)
#define OFF_YGH   ((size_t)0)
#define OFF_W1HI  ((size_t)16777216)
#define OFF_W1LO  ((size_t)(16777216 + 34603008))
#define OFF_M     ((size_t)16777216)
#define OFF_SPREV ((size_t)50331648)
#define OFF_W2HI  ((size_t)16777216)
#define OFF_W2LO  ((size_t)33554432)
#define OFF_PROJ  ((size_t)85983232)
#define OFF_XBC   ((size_t)155189248)
#define OFF_DT    ((size_t)189792256)
#define OFF_CD    ((size_t)190316544)
#define OFF_Y     ((size_t)190840832)
#define OFF_YGL   ((size_t)224395264)
// M region overlaps w1_hi (dead after gemm1); w2 regions overlap M/Sprev
// region writers all run after their previous readers. Total ~230 MB.

extern "C" void kernel_launch(void* const* d_in, const int* in_sizes, int n_in,
                              void* d_out, int out_size, void* d_ws, size_t ws_size,
                              hipStream_t stream) {
    (void)in_sizes; (void)n_in; (void)out_size; (void)ws_size;
    const float* hs   = (const float*)d_in[0];
    const float* w1   = (const float*)d_in[1];
    const float* cw   = (const float*)d_in[2];
    const float* cb   = (const float*)d_in[3];
    const float* dtb  = (const float*)d_in[4];
    const float* alog = (const float*)d_in[5];
    const float* Dp   = (const float*)d_in[6];
    const float* nw   = (const float*)d_in[7];
    const float* w2   = (const float*)d_in[8];
    float* out = (float*)d_out;
    char* ws = (char*)d_ws;

    unsigned short* hs_hi = (unsigned short*)(ws + OFF_HSHI);
    unsigned short* hs_lo = (unsigned short*)(ws + OFF_HSLO);
    unsigned short* w1_hi = (unsigned short*)(ws + OFF_W1HI);
    unsigned short* w1_lo = (unsigned short*)(ws + OFF_W1LO);
    unsigned short* w2_hi = (unsigned short*)(ws + OFF_W2HI);
    unsigned short* w2_lo = (unsigned short*)(ws + OFF_W2LO);
    unsigned short* ygh   = (unsigned short*)(ws + OFF_YGH);
    unsigned short* ygl   = (unsigned short*)(ws + OFF_YGL);
    float* proj  = (float*)(ws + OFF_PROJ);
    float* xbc   = (float*)(ws + OFF_XBC);
    float* dtv   = (float*)(ws + OFF_DT);
    float* cdv   = (float*)(ws + OFF_CD);
    float* y     = (float*)(ws + OFF_Y);
    float* M     = (float*)(ws + OFF_M);
    float* Sprev = (float*)(ws + OFF_SPREV);

    // 1) splits: hs hi+lo; w1 hi (full, zero-padded); w1 lo only rows [8192,8448)
    k_split<<<16384, 256, 0, stream>>>(hs, hs_hi, hs_lo, 4194304L, 4194304L);
    k_split_hi<<<67584, 256, 0, stream>>>(w1, w1_hi, 17170432L, 17301504L);
    k_split_lo<<<2048, 256, 0, stream>>>(w1 + (size_t)8192 * 2048, w1_lo, 393216L, 524288L);

    // 2) in_proj: cols [0,8192) bf16-hi only; cols [8192,8448) 3-term split
    const unsigned short* w1_lo_base = w1_lo - (size_t)8192 * 2048;
    k_gemm_split<<<1056, 256, 0, stream>>>(hs_hi, hs_lo, w1_hi, w1_lo_base, proj,
                                           HIDDEN, LDPROJ, 16, 6, 8192);

    // 3) conv + silu; dt softplus + within-chunk cumsum
    k_conv<<<dim3(17, 256), 256, 0, stream>>>(proj, cw, cb, xbc);
    k_cum<<<512, 256, 0, stream>>>(proj, dtb, dtv, cdv);

    // 4) chunked SSD
    k_ssdA<<<dim3(NCHUNK, NHEADS), 256, 0, stream>>>(xbc, dtv, cdv, alog, Dp, y, M);
    k_state<<<1024, 256, 0, stream>>>(M, cdv, alog, Sprev);
    k_ssdC<<<dim3(NCHUNK, NHEADS), 256, 0, stream>>>(xbc, cdv, alog, Sprev, y);

    // 5) RMSNorm * silu(gate) + split to bf16
    k_norm<<<SEQLEN, 256, 0, stream>>>(y, proj, nw, ygh, ygl);

    // 6) split out_proj weights (w1/M regions dead by now)
    k_split<<<32768, 256, 0, stream>>>(w2, w2_hi, w2_lo, 8388608L, 8388608L);

    // 7) out = yg @ w2^T, full 3-term
    k_gemm_split<<<256, 256, 0, stream>>>(ygh, ygl, w2_hi, w2_lo, out,
                                          INTER, HIDDEN, 16, 4, 0);
}

// Round 5
// 632.460 us; speedup vs baseline: 1.2938x; 1.0841x over previous
//
#include <hip/hip_runtime.h>
#include <hip/hip_bf16.h>
#include <cstdint>
#include <cstddef>

// Problem constants
#define SEQLEN   2048
#define HIDDEN   2048
#define INTER    4096
#define NHEADS   64
#define NSTATE   64
#define CONVD    4224          // INTER + 2*64
#define LDPROJ   8448          // PROJ (8384) padded to 128-multiple
#define NCHUNK   32
#define CHUNK    64

typedef __attribute__((ext_vector_type(8))) short bf16x8_t;
typedef __attribute__((ext_vector_type(4))) float f32x4_t;

__device__ __forceinline__ void cp16(void* lds, const void* g) {
    __builtin_amdgcn_global_load_lds(
        (const __attribute__((address_space(1))) unsigned int*)g,
        (__attribute__((address_space(3))) unsigned int*)lds, 16, 0, 0);
}

// ---------------- split fp32 -> bf16 (hi, lo) ----------------
__global__ void k_split(const float* __restrict__ in, unsigned short* __restrict__ hi,
                        unsigned short* __restrict__ lo, long nvalid, long ntotal) {
    long i = (long)blockIdx.x * 256 + threadIdx.x;
    if (i >= ntotal) return;
    float x = (i < nvalid) ? in[i] : 0.0f;
    __hip_bfloat16 h = __float2bfloat16(x);
    float hf = __bfloat162float(h);
    __hip_bfloat16 l = __float2bfloat16(x - hf);
    hi[i] = *reinterpret_cast<unsigned short*>(&h);
    lo[i] = *reinterpret_cast<unsigned short*>(&l);
}

__global__ void k_split_hi(const float* __restrict__ in, unsigned short* __restrict__ hi,
                           long nvalid, long ntotal) {
    long i = (long)blockIdx.x * 256 + threadIdx.x;
    if (i >= ntotal) return;
    float x = (i < nvalid) ? in[i] : 0.0f;
    __hip_bfloat16 h = __float2bfloat16(x);
    hi[i] = *reinterpret_cast<unsigned short*>(&h);
}

__global__ void k_split_lo(const float* __restrict__ in, unsigned short* __restrict__ lo,
                           long nvalid, long ntotal) {
    long i = (long)blockIdx.x * 256 + threadIdx.x;
    if (i >= ntotal) return;
    float x = (i < nvalid) ? in[i] : 0.0f;
    __hip_bfloat16 h = __float2bfloat16(x);
    float hf = __bfloat162float(h);
    __hip_bfloat16 l = __float2bfloat16(x - hf);
    lo[i] = *reinterpret_cast<unsigned short*>(&l);
}

// ---------------- hi-only bf16 GEMM: C[M,N] (+)= A[M,K] * B[N,K]^T --------------
// 128x128 tile, 1-barrier dbuf pipeline, 32 KB LDS -> 4 blocks/CU.
// Split-K via blockIdx.y: each k-slice does K/gridDim.y; if gridDim.y>1,
// epilogue atomicAdds into C (caller zeroes C first).
__global__ __launch_bounds__(256, 4)
void k_gemm_hi(const unsigned short* __restrict__ Ah, const unsigned short* __restrict__ Bh,
               float* __restrict__ C, int K, int ldc, int mb_count, int strip_w) {
    __shared__ unsigned short sA[2][4096];   // [buf][128x32]
    __shared__ unsigned short sB[2][4096];

    const int tid  = threadIdx.x;
    const int lane = tid & 63;
    const int w    = tid >> 6;
    const int wm   = w >> 1, wn = w & 1;

    const int span   = mb_count * strip_w;
    const int strip  = blockIdx.x / span;
    const int within = blockIdx.x % span;
    const int mblk = within % mb_count;
    const int nblk = strip * strip_w + within / mb_count;
    const long bm  = (long)mblk * 128;
    const long bn  = (long)nblk * 128;

    const int KS    = gridDim.y;
    const int Kc    = K / KS;
    const int kbase = blockIdx.y * Kc;

    f32x4_t acc[4][4];
#pragma unroll
    for (int i = 0; i < 4; ++i)
#pragma unroll
        for (int j = 0; j < 4; ++j) acc[i][j] = (f32x4_t){0.f, 0.f, 0.f, 0.f};

    const int srow = lane & 15;          // staging row-in-chunk
    const int c8   = (lane >> 4) << 3;   // staging k element offset

    auto stage = [&](int k0, int buf) {
#pragma unroll
        for (int j = 0; j < 2; ++j) {
            const int chunk = j * 4 + w;          // wave-uniform
            const int r     = chunk * 16 + srow;
            const long gA   = (bm + r) * (long)K + k0 + c8;
            const long gB   = (bn + r) * (long)K + k0 + c8;
            const int lbase = chunk * 512;
            cp16(&sA[buf][lbase], Ah + gA);
            cp16(&sB[buf][lbase], Bh + gB);
        }
    };

    const int NK = Kc >> 5;
    stage(kbase, 0);

    for (int it = 0; it < NK; ++it) {
        const int cur = it & 1;
        __syncthreads();

        bf16x8_t fah[4], fbh[4];
#pragma unroll
        for (int mi = 0; mi < 4; ++mi)
            fah[mi] = *(const bf16x8_t*)&sA[cur][(wm * 4 + mi) * 512 + lane * 8];
#pragma unroll
        for (int ni = 0; ni < 4; ++ni)
            fbh[ni] = *(const bf16x8_t*)&sB[cur][(wn * 4 + ni) * 512 + lane * 8];

        if (it + 1 < NK) stage(kbase + ((it + 1) << 5), cur ^ 1);

#pragma unroll
        for (int mi = 0; mi < 4; ++mi)
#pragma unroll
            for (int ni = 0; ni < 4; ++ni)
                acc[mi][ni] = __builtin_amdgcn_mfma_f32_16x16x32_bf16(fah[mi], fbh[ni], acc[mi][ni], 0, 0, 0);
    }

    // epilogue: D mapping col = lane&15, row = (lane>>4)*4 + reg  [m89-verified]
    const int col = lane & 15;
    const int rq  = (lane >> 4) << 2;
    if (KS > 1) {
#pragma unroll
        for (int mi = 0; mi < 4; ++mi)
#pragma unroll
            for (int ni = 0; ni < 4; ++ni) {
                long mb_ = bm + wm * 64 + mi * 16 + rq;
                long nb_ = bn + wn * 64 + ni * 16 + col;
#pragma unroll
                for (int r = 0; r < 4; ++r)
                    atomicAdd(&C[(mb_ + r) * (long)ldc + nb_], acc[mi][ni][r]);
            }
    } else {
#pragma unroll
        for (int mi = 0; mi < 4; ++mi)
#pragma unroll
            for (int ni = 0; ni < 4; ++ni) {
                long mb_ = bm + wm * 64 + mi * 16 + rq;
                long nb_ = bn + wn * 64 + ni * 16 + col;
#pragma unroll
                for (int r = 0; r < 4; ++r) C[(mb_ + r) * (long)ldc + nb_] = acc[mi][ni][r];
            }
    }
}

// ---------------- 3-term split-bf16 GEMM (R4-proven) for sensitive columns -------
// bn = nbase + nblk*128. 64 KB LDS, used only for a 32-block dispatch.
__global__ __launch_bounds__(256, 2)
void k_gemm_split(const unsigned short* __restrict__ Ah, const unsigned short* __restrict__ Al,
                  const unsigned short* __restrict__ Bh, const unsigned short* __restrict__ Bl,
                  float* __restrict__ C, int K, int ldc,
                  int mb_count, int nbase) {
    __shared__ unsigned short sA[2][2][4096];   // [buf][hi/lo][128x32]
    __shared__ unsigned short sB[2][2][4096];

    const int tid  = threadIdx.x;
    const int lane = tid & 63;
    const int w    = tid >> 6;
    const int wm   = w >> 1, wn = w & 1;

    const int mblk = blockIdx.x % mb_count;
    const int nblk = blockIdx.x / mb_count;
    const long bm  = (long)mblk * 128;
    const long bn  = (long)nbase + (long)nblk * 128;

    f32x4_t acc[4][4];
#pragma unroll
    for (int i = 0; i < 4; ++i)
#pragma unroll
        for (int j = 0; j < 4; ++j) acc[i][j] = (f32x4_t){0.f, 0.f, 0.f, 0.f};

    const int srow = lane & 15;
    const int c8   = (lane >> 4) << 3;

    auto stage = [&](int k0, int buf) {
#pragma unroll
        for (int j = 0; j < 2; ++j) {
            const int chunk = j * 4 + w;
            const int r     = chunk * 16 + srow;
            const long gA   = (bm + r) * (long)K + k0 + c8;
            const long gB   = (bn + r) * (long)K + k0 + c8;
            const int lbase = chunk * 512;
            cp16(&sA[buf][0][lbase], Ah + gA);
            cp16(&sB[buf][0][lbase], Bh + gB);
            cp16(&sA[buf][1][lbase], Al + gA);
            cp16(&sB[buf][1][lbase], Bl + gB);
        }
    };

    const int NK = K >> 5;
    stage(0, 0);

    for (int it = 0; it < NK; ++it) {
        const int cur = it & 1;
        __syncthreads();

        bf16x8_t fah[4], fbh[4], fal[4], fbl[4];
#pragma unroll
        for (int mi = 0; mi < 4; ++mi) {
            fah[mi] = *(const bf16x8_t*)&sA[cur][0][(wm * 4 + mi) * 512 + lane * 8];
            fal[mi] = *(const bf16x8_t*)&sA[cur][1][(wm * 4 + mi) * 512 + lane * 8];
        }
#pragma unroll
        for (int ni = 0; ni < 4; ++ni) {
            fbh[ni] = *(const bf16x8_t*)&sB[cur][0][(wn * 4 + ni) * 512 + lane * 8];
            fbl[ni] = *(const bf16x8_t*)&sB[cur][1][(wn * 4 + ni) * 512 + lane * 8];
        }

        if (it + 1 < NK) stage((it + 1) << 5, cur ^ 1);

#pragma unroll
        for (int mi = 0; mi < 4; ++mi)
#pragma unroll
            for (int ni = 0; ni < 4; ++ni) {
                acc[mi][ni] = __builtin_amdgcn_mfma_f32_16x16x32_bf16(fah[mi], fbh[ni], acc[mi][ni], 0, 0, 0);
                acc[mi][ni] = __builtin_amdgcn_mfma_f32_16x16x32_bf16(fah[mi], fbl[ni], acc[mi][ni], 0, 0, 0);
                acc[mi][ni] = __builtin_amdgcn_mfma_f32_16x16x32_bf16(fal[mi], fbh[ni], acc[mi][ni], 0, 0, 0);
            }
    }

    const int col = lane & 15;
    const int rq  = (lane >> 4) << 2;
#pragma unroll
    for (int mi = 0; mi < 4; ++mi)
#pragma unroll
        for (int ni = 0; ni < 4; ++ni) {
            long mb_ = bm + wm * 64 + mi * 16 + rq;
            long nb_ = bn + wn * 64 + ni * 16 + col;
#pragma unroll
            for (int r = 0; r < 4; ++r) C[(mb_ + r) * (long)ldc + nb_] = acc[mi][ni][r];
        }
}

// ---------------- causal depthwise conv (K=4) + SiLU: 8 timesteps/thread ----------
__global__ __launch_bounds__(256)
void k_conv(const float* __restrict__ proj, const float* __restrict__ cw,
            const float* __restrict__ cb, float* __restrict__ xbc) {
    int c  = blockIdx.x * 256 + threadIdx.x;
    int t0 = blockIdx.y * 8;
    if (c >= CONVD) return;
    const float cw0 = cw[c * 4], cw1 = cw[c * 4 + 1], cw2 = cw[c * 4 + 2], cw3 = cw[c * 4 + 3];
    const float b = cb[c];
    float h[11];
#pragma unroll
    for (int i = 0; i < 11; ++i) {
        int tt = t0 - 3 + i;
        h[i] = (tt >= 0) ? proj[(size_t)tt * LDPROJ + INTER + c] : 0.f;
    }
#pragma unroll
    for (int k = 0; k < 8; ++k) {
        float acc = b + h[k] * cw0 + h[k + 1] * cw1 + h[k + 2] * cw2 + h[k + 3] * cw3;
        float s = acc / (1.f + expf(-acc));
        xbc[(size_t)(t0 + k) * CONVD + c] = s;
    }
}

// ---------------- dt = softplus(raw + bias); cd = within-chunk inclusive cumsum ----
__global__ __launch_bounds__(256)
void k_cum(const float* __restrict__ proj, const float* __restrict__ dtb,
           float* __restrict__ dt, float* __restrict__ cd) {
    const int tid  = threadIdx.x;
    const int lane = tid & 63;
    const int wid  = blockIdx.x * 4 + (tid >> 6);
    const int c    = wid >> 6;
    const int h    = wid & 63;
    const int t    = c * CHUNK + lane;
    float raw = proj[(size_t)t * LDPROJ + 8320 + h] + dtb[h];
    float sp  = (raw > 20.f) ? raw : log1pf(expf(raw));
    float x = sp;
#pragma unroll
    for (int off = 1; off < 64; off <<= 1) {
        float v = __shfl_up(x, off, 64);
        if (lane >= off) x += v;
    }
    dt[t * 64 + h] = sp;
    cd[t * 64 + h] = x;
}

// ---------------- SSD intra-chunk: G = tril(CB^T ∘ decay), Y=G@X, M=(wB)^T@X ------
__global__ __launch_bounds__(256, 2)
void k_ssdA(const float* __restrict__ xbc, const float* __restrict__ dt,
            const float* __restrict__ cd, const float* __restrict__ alog,
            const float* __restrict__ Dp, float* __restrict__ y,
            float* __restrict__ M) {
    __shared__ float Xs[64][68];
    __shared__ float Bs[64][68];
    __shared__ float Cs[64][68];
    __shared__ float dts[64], cds[64], wts[64];
    float (*Gs)[68] = Cs;

    const int c = blockIdx.x, h = blockIdx.y;
    const int tid = threadIdx.x;
    const int tr = tid >> 4, tc = tid & 15;
    const int t0 = c * CHUNK;
    const float A = -__expf(alog[h]);

    for (int i = tid; i < 4096; i += 256) {
        int t = i >> 6, j = i & 63;
        size_t base = (size_t)(t0 + t) * CONVD;
        Xs[t][j] = xbc[base + h * 64 + j];
        Bs[t][j] = xbc[base + INTER + j];
        Cs[t][j] = xbc[base + INTER + 64 + j];
    }
    if (tid < 64) {
        dts[tid] = dt[(t0 + tid) * 64 + h];
        cds[tid] = cd[(t0 + tid) * 64 + h];
    }
    __syncthreads();
    if (tid < 64) wts[tid] = __expf(A * (cds[63] - cds[tid])) * dts[tid];

    float g[4][4];
#pragma unroll
    for (int i = 0; i < 4; ++i)
#pragma unroll
        for (int j = 0; j < 4; ++j) g[i][j] = 0.f;
    for (int n = 0; n < 64; n += 4) {
        float4 cv[4], bv[4];
#pragma unroll
        for (int i = 0; i < 4; ++i) cv[i] = *(const float4*)&Cs[tr * 4 + i][n];
#pragma unroll
        for (int j = 0; j < 4; ++j) bv[j] = *(const float4*)&Bs[tc * 4 + j][n];
#pragma unroll
        for (int i = 0; i < 4; ++i)
#pragma unroll
            for (int j = 0; j < 4; ++j)
                g[i][j] += cv[i].x * bv[j].x + cv[i].y * bv[j].y +
                           cv[i].z * bv[j].z + cv[i].w * bv[j].w;
    }
    __syncthreads();
#pragma unroll
    for (int i = 0; i < 4; ++i) {
        int t = tr * 4 + i;
#pragma unroll
        for (int j = 0; j < 4; ++j) {
            int tau = tc * 4 + j;
            float v = (tau <= t) ? g[i][j] * __expf(A * (cds[t] - cds[tau])) * dts[tau] : 0.f;
            Gs[t][tau] = v;
        }
    }
    __syncthreads();

    float accY[4][4], accM[4][4];
#pragma unroll
    for (int i = 0; i < 4; ++i)
#pragma unroll
        for (int j = 0; j < 4; ++j) { accY[i][j] = 0.f; accM[i][j] = 0.f; }

    for (int tau = 0; tau < 64; tau += 4) {
        float4 gv[4], xv[4];
#pragma unroll
        for (int i = 0; i < 4; ++i) gv[i] = *(const float4*)&Gs[tr * 4 + i][tau];
#pragma unroll
        for (int k = 0; k < 4; ++k) xv[k] = *(const float4*)&Xs[tau + k][tc * 4];
#pragma unroll
        for (int i = 0; i < 4; ++i) {
            accY[i][0] += gv[i].x * xv[0].x + gv[i].y * xv[1].x + gv[i].z * xv[2].x + gv[i].w * xv[3].x;
            accY[i][1] += gv[i].x * xv[0].y + gv[i].y * xv[1].y + gv[i].z * xv[2].y + gv[i].w * xv[3].y;
            accY[i][2] += gv[i].x * xv[0].z + gv[i].y * xv[1].z + gv[i].z * xv[2].z + gv[i].w * xv[3].z;
            accY[i][3] += gv[i].x * xv[0].w + gv[i].y * xv[1].w + gv[i].z * xv[2].w + gv[i].w * xv[3].w;
        }
#pragma unroll
        for (int k = 0; k < 4; ++k) {
            float wv = wts[tau + k];
            float4 bv = *(const float4*)&Bs[tau + k][tr * 4];
            float4 xk = xv[k];
            float wb0 = wv * bv.x, wb1 = wv * bv.y, wb2 = wv * bv.z, wb3 = wv * bv.w;
            accM[0][0] += wb0 * xk.x; accM[0][1] += wb0 * xk.y; accM[0][2] += wb0 * xk.z; accM[0][3] += wb0 * xk.w;
            accM[1][0] += wb1 * xk.x; accM[1][1] += wb1 * xk.y; accM[1][2] += wb1 * xk.z; accM[1][3] += wb1 * xk.w;
            accM[2][0] += wb2 * xk.x; accM[2][1] += wb2 * xk.y; accM[2][2] += wb2 * xk.z; accM[2][3] += wb2 * xk.w;
            accM[3][0] += wb3 * xk.x; accM[3][1] += wb3 * xk.y; accM[3][2] += wb3 * xk.z; accM[3][3] += wb3 * xk.w;
        }
    }

    const float Dv = Dp[h];
#pragma unroll
    for (int i = 0; i < 4; ++i) {
        int t = tr * 4 + i;
        float4 o;
        o.x = accY[i][0] + Dv * Xs[t][tc * 4 + 0];
        o.y = accY[i][1] + Dv * Xs[t][tc * 4 + 1];
        o.z = accY[i][2] + Dv * Xs[t][tc * 4 + 2];
        o.w = accY[i][3] + Dv * Xs[t][tc * 4 + 3];
        *(float4*)&y[(size_t)(t0 + t) * INTER + h * 64 + tc * 4] = o;
    }
    size_t mbase = ((size_t)(c * 64 + h)) << 12;
#pragma unroll
    for (int i = 0; i < 4; ++i) {
        float4 o = { accM[i][0], accM[i][1], accM[i][2], accM[i][3] };
        *(float4*)&M[mbase + (size_t)(tr * 4 + i) * 64 + tc * 4] = o;
    }
}

// ---------------- sequential chunk-state propagation ----------------
__global__ __launch_bounds__(256)
void k_state(const float* __restrict__ M, const float* __restrict__ cd,
             const float* __restrict__ alog, float* __restrict__ Sprev) {
    const int g  = blockIdx.x * 256 + threadIdx.x;
    const int h  = g >> 12;
    const int np = g & 4095;
    const float A = -__expf(alog[h]);
    float s = 0.f;
#pragma unroll 1
    for (int c = 0; c < NCHUNK; ++c) {
        size_t idx = (((size_t)(c * 64 + h)) << 12) + np;
        Sprev[idx] = s;
        float decay = __expf(A * cd[((c * CHUNK + 63) * 64) + h]);
        s = decay * s + M[idx];
    }
}

// ---------------- SSD inter-chunk: y += exp(A*cd_t) * C_t . S_prev ----------------
__global__ __launch_bounds__(256, 2)
void k_ssdC(const float* __restrict__ xbc, const float* __restrict__ cd,
            const float* __restrict__ alog, const float* __restrict__ Sprev,
            float* __restrict__ y) {
    __shared__ float Ss[64][68];
    __shared__ float Cs[64][68];
    __shared__ float cds[64];
    const int c = blockIdx.x, h = blockIdx.y;
    const int tid = threadIdx.x;
    const int tr = tid >> 4, tc = tid & 15;
    const int t0 = c * CHUNK;
    const float A = -__expf(alog[h]);

    size_t sbase = ((size_t)(c * 64 + h)) << 12;
    for (int i = tid; i < 4096; i += 256) {
        int n = i >> 6, p = i & 63;
        Ss[n][p] = Sprev[sbase + i];
        Cs[n][p] = xbc[(size_t)(t0 + n) * CONVD + INTER + 64 + p];
    }
    if (tid < 64) cds[tid] = cd[(t0 + tid) * 64 + h];
    __syncthreads();

    float acc[4][4];
#pragma unroll
    for (int i = 0; i < 4; ++i)
#pragma unroll
        for (int j = 0; j < 4; ++j) acc[i][j] = 0.f;

    for (int n = 0; n < 64; n += 4) {
        float4 cv[4], sv[4];
#pragma unroll
        for (int i = 0; i < 4; ++i) cv[i] = *(const float4*)&Cs[tr * 4 + i][n];
#pragma unroll
        for (int k = 0; k < 4; ++k) sv[k] = *(const float4*)&Ss[n + k][tc * 4];
#pragma unroll
        for (int i = 0; i < 4; ++i) {
            acc[i][0] += cv[i].x * sv[0].x + cv[i].y * sv[1].x + cv[i].z * sv[2].x + cv[i].w * sv[3].x;
            acc[i][1] += cv[i].x * sv[0].y + cv[i].y * sv[1].y + cv[i].z * sv[2].y + cv[i].w * sv[3].y;
            acc[i][2] += cv[i].x * sv[0].z + cv[i].y * sv[1].z + cv[i].z * sv[2].z + cv[i].w * sv[3].z;
            acc[i][3] += cv[i].x * sv[0].w + cv[i].y * sv[1].w + cv[i].z * sv[2].w + cv[i].w * sv[3].w;
        }
    }

#pragma unroll
    for (int i = 0; i < 4; ++i) {
        int t = tr * 4 + i;
        float sc = __expf(A * cds[t]);
        size_t yi = (size_t)(t0 + t) * INTER + h * 64 + tc * 4;
        float4 cur = *(const float4*)&y[yi];
        cur.x += sc * acc[i][0];
        cur.y += sc * acc[i][1];
        cur.z += sc * acc[i][2];
        cur.w += sc * acc[i][3];
        *(float4*)&y[yi] = cur;
    }
}

// ---------------- RMSNorm * silu(gate), then bf16-hi ----------------
__global__ __launch_bounds__(256)
void k_norm(const float* __restrict__ y, const float* __restrict__ proj,
            const float* __restrict__ nw, unsigned short* __restrict__ ygh) {
    __shared__ float red[4];
    const int t = blockIdx.x, tid = threadIdx.x;
    float sum = 0.f;
    for (int i = tid; i < INTER; i += 256) {
        float v = y[(size_t)t * INTER + i];
        sum += v * v;
    }
#pragma unroll
    for (int off = 32; off >= 1; off >>= 1) sum += __shfl_xor(sum, off, 64);
    if ((tid & 63) == 0) red[tid >> 6] = sum;
    __syncthreads();
    float var = (red[0] + red[1] + red[2] + red[3]) * (1.f / INTER);
    float rs  = rsqrtf(var + 1e-6f);
    for (int i = tid; i < INTER; i += 256) {
        float v = y[(size_t)t * INTER + i] * rs * nw[i];
        float g = proj[(size_t)t * LDPROJ + i];
        float o = v * (g / (1.f + expf(-g)));
        __hip_bfloat16 hh = __float2bfloat16(o);
        ygh[(size_t)t * INTER + i] = *reinterpret_cast<unsigned short*>(&hh);
    }
}

// ---------------- workspace layout (bytes) ----------------
#define OFF_HSHI  ((size_t)0)           // 8,388,608
#define OFF_HSLO  ((size_t)8388608)     // 8,388,608
#define OFF_YGH   ((size_t)16777216)    // 16,777,216
#define OFF_W1HI  ((size_t)33554432)    // 34,603,008 (8448 rows x 2048 bf16)
#define OFF_M     ((size_t)33554432)    // 33,554,432 (reuses W1HI after gemm1)
#define OFF_W1LO  ((size_t)68157440)    // 1,048,576  (rows [8192,8448) x 2048)
#define OFF_SPREV ((size_t)69206016)    // 33,554,432
#define OFF_PROJ  ((size_t)102760448)   // 69,206,016
#define OFF_XBC   ((size_t)171966464)   // 34,603,008
#define OFF_DT    ((size_t)206569472)   // 524,288
#define OFF_CD    ((size_t)207093760)   // 524,288
#define OFF_Y     ((size_t)207618048)   // 33,554,432
#define OFF_W2HI  ((size_t)207618048)   // 16,777,216 (reuses Y after k_norm)
// total 241,172,480 (identical footprint to R4)

extern "C" void kernel_launch(void* const* d_in, const int* in_sizes, int n_in,
                              void* d_out, int out_size, void* d_ws, size_t ws_size,
                              hipStream_t stream) {
    (void)in_sizes; (void)n_in; (void)out_size; (void)ws_size;
    const float* hs   = (const float*)d_in[0];
    const float* w1   = (const float*)d_in[1];
    const float* cw   = (const float*)d_in[2];
    const float* cb   = (const float*)d_in[3];
    const float* dtb  = (const float*)d_in[4];
    const float* alog = (const float*)d_in[5];
    const float* Dp   = (const float*)d_in[6];
    const float* nw   = (const float*)d_in[7];
    const float* w2   = (const float*)d_in[8];
    float* out = (float*)d_out;
    char* ws = (char*)d_ws;

    unsigned short* hs_hi = (unsigned short*)(ws + OFF_HSHI);
    unsigned short* hs_lo = (unsigned short*)(ws + OFF_HSLO);
    unsigned short* w1_hi = (unsigned short*)(ws + OFF_W1HI);
    unsigned short* w1_lo = (unsigned short*)(ws + OFF_W1LO);
    unsigned short* w2_hi = (unsigned short*)(ws + OFF_W2HI);
    unsigned short* ygh   = (unsigned short*)(ws + OFF_YGH);
    float* proj  = (float*)(ws + OFF_PROJ);
    float* xbc   = (float*)(ws + OFF_XBC);
    float* dtv   = (float*)(ws + OFF_DT);
    float* cdv   = (float*)(ws + OFF_CD);
    float* y     = (float*)(ws + OFF_Y);
    float* M     = (float*)(ws + OFF_M);
    float* Sprev = (float*)(ws + OFF_SPREV);

    // 1) splits: hs hi+lo; w1 hi (full 8448 rows, zero-padded); w1 lo rows [8192,8448)
    k_split<<<16384, 256, 0, stream>>>(hs, hs_hi, hs_lo, 4194304L, 4194304L);
    k_split_hi<<<67584, 256, 0, stream>>>(w1, w1_hi, 17170432L, 17301504L);
    k_split_lo<<<2048, 256, 0, stream>>>(w1 + (size_t)8192 * 2048, w1_lo, 393216L, 524288L);

    // 2a) in_proj bulk: cols [0,8192) hi-only, 32 KB LDS, 4 blocks/CU, grid=1024
    k_gemm_hi<<<dim3(1024, 1), 256, 0, stream>>>(hs_hi, w1_hi, proj, HIDDEN, LDPROJ, 16, 8);
    // 2b) sensitive cols [8192,8448) (B, C, dt, pad): 3-term split, 32 blocks
    const unsigned short* w1_lo_base = w1_lo - (size_t)8192 * 2048;
    k_gemm_split<<<32, 256, 0, stream>>>(hs_hi, hs_lo, w1_hi, w1_lo_base, proj,
                                         HIDDEN, LDPROJ, 16, 8192);

    // 3) conv + silu; dt softplus + within-chunk cumsum
    k_conv<<<dim3(17, 256), 256, 0, stream>>>(proj, cw, cb, xbc);
    k_cum<<<512, 256, 0, stream>>>(proj, dtb, dtv, cdv);

    // 4) chunked SSD
    k_ssdA<<<dim3(NCHUNK, NHEADS), 256, 0, stream>>>(xbc, dtv, cdv, alog, Dp, y, M);
    k_state<<<1024, 256, 0, stream>>>(M, cdv, alog, Sprev);
    k_ssdC<<<dim3(NCHUNK, NHEADS), 256, 0, stream>>>(xbc, cdv, alog, Sprev, y);

    // 5) RMSNorm * silu(gate) -> bf16 hi (y dead afterwards)
    k_norm<<<SEQLEN, 256, 0, stream>>>(y, proj, nw, ygh);

    // 6) split out_proj weights into the dead y region
    k_split_hi<<<32768, 256, 0, stream>>>(w2, w2_hi, 8388608L, 8388608L);

    // 7) out_proj: hi-only, split-K=4, atomic accumulate into zeroed out
    hipMemsetAsync(out, 0, (size_t)SEQLEN * HIDDEN * sizeof(float), stream);
    k_gemm_hi<<<dim3(256, 4), 256, 0, stream>>>(ygh, w2_hi, out, INTER, HIDDEN, 16, 16);
}